// Round 2
// baseline (147.403 us; speedup 1.0000x reference)
//
#include <hip/hip_runtime.h>
#include <math.h>

#define BB 64
#define SS 8192
#define IN_DIM 512
#define OUT_DIM 128
#define DVV 128
#define CHUNK 256
#define NCHUNK (SS / CHUNK)   // 32

// Kernel 1: qt[b] = (Wk @ (q[b] @ Wq)) / sqrt(OUT_DIM)   (512 threads, 4-way split-K)
__global__ __launch_bounds__(512) void qt_kernel(const float* __restrict__ q,
                          const float* __restrict__ Wq,
                          const float* __restrict__ Wk,
                          float* __restrict__ qt) {
    int b = blockIdx.x;
    int t = threadIdx.x;
    int e = t & 127;          // output index
    int h = t >> 7;           // split 0..3
    __shared__ float part[4][OUT_DIM];
    __shared__ float qs[OUT_DIM];

    const float* qb = q + (size_t)b * IN_DIM;
    float acc = 0.f;
    for (int i = h * (IN_DIM / 4); i < (h + 1) * (IN_DIM / 4); ++i)
        acc = fmaf(qb[i], Wq[(size_t)i * OUT_DIM + e], acc);
    part[h][e] = acc;
    __syncthreads();
    if (h == 0) qs[e] = part[0][e] + part[1][e] + part[2][e] + part[3][e];
    __syncthreads();

    // qt[d] = sum_e Wk[d][e] * query[e]
    float a2 = 0.f;
    const float* wkrow = Wk + (size_t)e * OUT_DIM;
    for (int i = h * (OUT_DIM / 4); i < (h + 1) * (OUT_DIM / 4); ++i)
        a2 = fmaf(wkrow[i], qs[i], a2);
    part[h][e] = a2;
    __syncthreads();
    if (h == 0)
        qt[(size_t)b * OUT_DIM + e] =
            (part[0][e] + part[1][e] + part[2][e] + part[3][e]) * 0.08838834764831845f;
}

// Kernel 2: fused online-softmax streaming kernel.
// Each block: one (b, chunk of 256 rows). 8 groups of 32 lanes; group g owns
// rows g+8j. Per row: load k-row + v-row (float4/lane), dot+butterfly for
// score, online (m,l,acc) update in registers. No barriers in the main loop.
__global__ __launch_bounds__(256) void partial_kernel(
    const float* __restrict__ k, const float* __restrict__ v,
    const float* __restrict__ qt, float* __restrict__ ml,
    float* __restrict__ ctx) {
    int blk = blockIdx.x;
    int b = blk / NCHUNK;
    int c = blk % NCHUNK;
    int s0 = c * CHUNK;
    int t = threadIdx.x;
    int g = t >> 5;          // group 0..7
    int l32 = t & 31;

    __shared__ float4 qts4[OUT_DIM / 4];
    __shared__ float gm[8], gl[8];
    __shared__ float4 gacc[8][32];

    if (t < OUT_DIM / 4)
        qts4[t] = ((const float4*)(qt + (size_t)b * OUT_DIM))[t];
    __syncthreads();
    float4 qv = qts4[l32];

    const float4* k4 = (const float4*)(k + (size_t)b * SS * OUT_DIM);
    const float4* v4 = (const float4*)(v + (size_t)b * SS * DVV);

    float m = -INFINITY, l = 0.f;
    float4 acc = make_float4(0.f, 0.f, 0.f, 0.f);

    #pragma unroll 4
    for (int j = 0; j < CHUNK / 8; ++j) {
        int i = s0 + g + 8 * j;
        float4 kv = k4[(size_t)i * (OUT_DIM / 4) + l32];
        float4 vv = v4[(size_t)i * (DVV / 4) + l32];
        float p = kv.x * qv.x + kv.y * qv.y + kv.z * qv.z + kv.w * qv.w;
        p += __shfl_xor(p, 1);
        p += __shfl_xor(p, 2);
        p += __shfl_xor(p, 4);
        p += __shfl_xor(p, 8);
        p += __shfl_xor(p, 16);
        float mnew = fmaxf(m, p);
        float cr = __expf(m - mnew);   // 1.0 when m unchanged (exact)
        float e = __expf(p - mnew);
        l = l * cr + e;
        acc.x = fmaf(acc.x, cr, e * vv.x);
        acc.y = fmaf(acc.y, cr, e * vv.y);
        acc.z = fmaf(acc.z, cr, e * vv.z);
        acc.w = fmaf(acc.w, cr, e * vv.w);
        m = mnew;
    }

    // block combine across the 8 groups (m,l uniform within a group)
    if (l32 == 0) gm[g] = m;
    __syncthreads();
    float M = gm[0];
    #pragma unroll
    for (int i = 1; i < 8; ++i) M = fmaxf(M, gm[i]);
    float scale = __expf(m - M);
    if (l32 == 0) gl[g] = l * scale;
    float4 sa;
    sa.x = acc.x * scale; sa.y = acc.y * scale;
    sa.z = acc.z * scale; sa.w = acc.w * scale;
    gacc[g][l32] = sa;
    __syncthreads();

    if (t < 32) {
        float4 r = gacc[0][t];
        #pragma unroll
        for (int i2 = 1; i2 < 8; ++i2) {
            float4 o = gacc[i2][t];
            r.x += o.x; r.y += o.y; r.z += o.z; r.w += o.w;
        }
        ((float4*)(ctx + ((size_t)(b * NCHUNK + c)) * DVV))[t] = r;
    }
    if (t == 0) {
        float L = gl[0];
        #pragma unroll
        for (int i3 = 1; i3 < 8; ++i3) L += gl[i3];
        ml[(b * NCHUNK + c) * 2 + 0] = M;
        ml[(b * NCHUNK + c) * 2 + 1] = L;
    }
}

// Kernel 3: merge chunk partials with max-rescaling
__global__ void combine_kernel(const float* __restrict__ ml,
                               const float* __restrict__ ctx,
                               float* __restrict__ out) {
    int b = blockIdx.x;
    int t = threadIdx.x;  // 128
    __shared__ float ms, ls;
    float m = -INFINITY;
    if (t < NCHUNK) m = ml[(b * NCHUNK + t) * 2];
    for (int d = 1; d < 32; d <<= 1) m = fmaxf(m, __shfl_xor(m, d));
    if (t == 0) ms = m;
    __syncthreads();
    m = ms;
    float l = 0.f;
    if (t < NCHUNK)
        l = ml[(b * NCHUNK + t) * 2 + 1] * __expf(ml[(b * NCHUNK + t) * 2] - m);
    for (int d = 1; d < 32; d <<= 1) l += __shfl_xor(l, d);
    if (t == 0) ls = l;
    __syncthreads();
    l = ls;
    float acc = 0.f;
    for (int c2 = 0; c2 < NCHUNK; ++c2) {
        float w = __expf(ml[(b * NCHUNK + c2) * 2] - m);
        acc = fmaf(ctx[((size_t)(b * NCHUNK + c2)) * DVV + t], w, acc);
    }
    out[(size_t)b * DVV + t] = acc / l;
}

extern "C" void kernel_launch(void* const* d_in, const int* in_sizes, int n_in,
                              void* d_out, int out_size, void* d_ws, size_t ws_size,
                              hipStream_t stream) {
    const float* k  = (const float*)d_in[0];
    const float* q  = (const float*)d_in[1];
    const float* v  = (const float*)d_in[2];
    const float* Wk = (const float*)d_in[3];
    const float* Wq = (const float*)d_in[4];
    float* out = (float*)d_out;

    float* qt  = (float*)d_ws;                 // B*128 floats
    float* ml  = qt + BB * OUT_DIM;            // B*NCHUNK*2 floats
    float* ctx = ml + BB * NCHUNK * 2;         // B*NCHUNK*128 floats (~1 MB total)

    qt_kernel<<<BB, 512, 0, stream>>>(q, Wq, Wk, qt);
    partial_kernel<<<BB * NCHUNK, 256, 0, stream>>>(k, v, qt, ml, ctx);
    combine_kernel<<<BB, DVV, 0, stream>>>(ml, ctx, out);
}